// Round 1
// baseline (682.844 us; speedup 1.0000x reference)
//
#include <hip/hip_runtime.h>

typedef __attribute__((ext_vector_type(8))) short short8;
typedef __attribute__((ext_vector_type(4))) short short4_;
typedef __attribute__((ext_vector_type(4))) float f32x4;

#define AS1 __attribute__((address_space(1)))
#define AS3 __attribute__((address_space(3)))
#define GLD16(g, l) __builtin_amdgcn_global_load_lds((const AS1 void*)(g), (AS3 void*)(l), 16, 0, 0)

#define C2 0.12751743f  /* log2(e)/sqrt(128) */

__device__ __forceinline__ unsigned short f2bf(float f) {
  unsigned int u = __float_as_uint(f);
  u += 0x7fffu + ((u >> 16) & 1u);   // RNE
  return (unsigned short)(u >> 16);
}

// ---------------- weight transpose: [K][N] f32 -> [N][K] bf16 ----------------
__global__ __launch_bounds__(256) void k_transpose_w(
    const float* __restrict__ wq, const float* __restrict__ wk,
    const float* __restrict__ wv, const float* __restrict__ wo,
    unsigned short* __restrict__ wqkvT, unsigned short* __restrict__ woT)
{
  __shared__ float tile[64][65];
  const int z = blockIdx.z;
  const float* src = (z == 0) ? wq : (z == 1) ? wk : (z == 2) ? wv : wo;
  unsigned short* dst = (z == 3) ? woT : (wqkvT + (size_t)z * 2048 * 2048);
  const int k0 = blockIdx.y * 64, n0 = blockIdx.x * 64;
  const int tid = threadIdx.x;
#pragma unroll
  for (int p = 0; p < 4; ++p) {
    const int r = p * 16 + (tid >> 4);
    const int c = (tid & 15) * 4;
    f32x4 v = *(const f32x4*)(src + (size_t)(k0 + r) * 2048 + n0 + c);
    tile[r][c + 0] = v[0]; tile[r][c + 1] = v[1];
    tile[r][c + 2] = v[2]; tile[r][c + 3] = v[3];
  }
  __syncthreads();
#pragma unroll
  for (int p = 0; p < 2; ++p) {
    const int task = tid + p * 256;
    const int n = task >> 3;
    const int kc = (task & 7) * 8;
    short8 ov;
#pragma unroll
    for (int j = 0; j < 8; ++j) ov[j] = (short)f2bf(tile[kc + j][n]);
    *(short8*)(dst + (size_t)(n0 + n) * 2048 + k0 + kc) = ov;
  }
}

// ------------- convert x / cache_k / cache_v f32 -> bf16 (cache into concat KV) -------------
__global__ __launch_bounds__(256) void k_convert(
    const float* __restrict__ x, const float* __restrict__ ck, const float* __restrict__ cv,
    unsigned short* __restrict__ xbf, unsigned short* __restrict__ kfull,
    unsigned short* __restrict__ vfull)
{
  const int z = blockIdx.y;
  const size_t idx = ((size_t)blockIdx.x * 256 + threadIdx.x) * 8;
  const float* src = (z == 0) ? x : (z == 1) ? ck : cv;
  f32x4 a = *(const f32x4*)(src + idx);
  f32x4 b = *(const f32x4*)(src + idx + 4);
  short8 ov;
#pragma unroll
  for (int j = 0; j < 4; ++j) { ov[j] = (short)f2bf(a[j]); ov[j + 4] = (short)f2bf(b[j]); }
  unsigned short* dp; size_t di;
  if (z == 0) { dp = xbf; di = idx; }
  else {
    const size_t r = idx >> 11, cl = idx & 2047;
    const size_t orow = r + (r & ~(size_t)2047);   // cache rows -> [b*4096 + p]
    di = orow * 2048 + cl;
    dp = (z == 1) ? kfull : vfull;
  }
  *(short8*)(dp + di) = ov;
}

// ---------------- GEMM: C[M,N] = A[M,K] * BT[N,K]^T + bias ----------------
// MODE 0: fused QKV, bf16 out with q / k_new / v_new routing (N=6144)
// MODE 1: f32 out + bias (final projection)
template <int MODE>
__global__ __launch_bounds__(256, 2) void k_gemm(
    const unsigned short* __restrict__ A, const unsigned short* __restrict__ BT,
    unsigned short* __restrict__ Oq, unsigned short* __restrict__ Ok,
    unsigned short* __restrict__ Ov, float* __restrict__ Of,
    const float* __restrict__ b0, const float* __restrict__ b1,
    const float* __restrict__ b2, int K)
{
  __shared__ unsigned short Ah[128 * 32];
  __shared__ unsigned short Bh[128 * 32];
  const int tid = threadIdx.x;
  const int l = tid & 63, w = tid >> 6;
  const int l15 = l & 15, g = l >> 4;
  const int wr = (w >> 1) * 64, wc = (w & 1) * 64;
  const int bm = blockIdx.y, bn = blockIdx.x;
  const unsigned short* Ab = A + (size_t)bm * 128 * K;
  const unsigned short* Bb = BT + (size_t)bn * 128 * K;
  const int srow = l >> 2;          // 0..15 row within 16-row chunk
  const int scol = (l & 3) * 8;     // bf16 col within BK=32
  f32x4 acc[4][4];
#pragma unroll
  for (int i = 0; i < 4; ++i)
#pragma unroll
    for (int j = 0; j < 4; ++j)
#pragma unroll
      for (int e = 0; e < 4; ++e) acc[i][j][e] = 0.f;

  for (int kt = 0; kt < K; kt += 32) {
#pragma unroll
    for (int cc = 0; cc < 2; ++cc) {
      const int c = w + cc * 4;     // chunk 0..7 (16 rows each)
      GLD16(Ab + (size_t)(c * 16 + srow) * K + kt + scol, &Ah[c * 512]);
      GLD16(Bb + (size_t)(c * 16 + srow) * K + kt + scol, &Bh[c * 512]);
    }
    __syncthreads();
    short8 af[4], bf[4];
#pragma unroll
    for (int i = 0; i < 4; ++i) {
      af[i] = *(const short8*)&Ah[(wr + i * 16 + l15) * 32 + g * 8];
      bf[i] = *(const short8*)&Bh[(wc + i * 16 + l15) * 32 + g * 8];
    }
#pragma unroll
    for (int i = 0; i < 4; ++i)
#pragma unroll
      for (int j = 0; j < 4; ++j)
        acc[i][j] = __builtin_amdgcn_mfma_f32_16x16x32_bf16(af[i], bf[j], acc[i][j], 0, 0, 0);
    __syncthreads();
  }

  const int rbase = bm * 128 + wr + g * 4;
  if (MODE == 0) {
    const int nglob = bn * 128;
    const int which = nglob >> 11;           // 0=q,1=k,2=v (uniform per block)
    const int ncol0 = nglob & 2047;
    unsigned short* dst = (which == 0) ? Oq : (which == 1) ? Ok : Ov;
    const float* bias = (which == 0) ? b0 : (which == 1) ? b1 : b2;
#pragma unroll
    for (int j = 0; j < 4; ++j) {
      const int cc = ncol0 + wc + j * 16 + l15;
      const float bb = bias[cc];
#pragma unroll
      for (int i = 0; i < 4; ++i) {
#pragma unroll
        for (int ii = 0; ii < 4; ++ii) {
          const int rr = rbase + i * 16 + ii;
          const size_t orow = (which == 0) ? (size_t)rr
                                           : (size_t)(rr + (rr & ~2047) + 2048);
          dst[orow * 2048 + cc] = f2bf(acc[i][j][ii] + bb);
        }
      }
    }
  } else {
#pragma unroll
    for (int j = 0; j < 4; ++j) {
      const int cc = bn * 128 + wc + j * 16 + l15;
      const float bb = b0[cc];
#pragma unroll
      for (int i = 0; i < 4; ++i) {
#pragma unroll
        for (int ii = 0; ii < 4; ++ii) {
          const int rr = rbase + i * 16 + ii;
          Of[(size_t)rr * 2048 + cc] = acc[i][j][ii] + bb;
        }
      }
    }
  }
}

// ---------------- flash attention ----------------
// grid (32 q-tiles, 32 b*h), 4 waves x 16 q-rows. KBLK=128 keys/tile.
// Swapped QK^T: S^T = mfma(A=K, B=Q^T) -> lane holds col q = l&15 (softmax stats lane-local).
// PV uses 16x16x32 with V^T columns PERMUTED (vcol = 8g+4h+i for key row 16h+4g+i) so
// the P D-registers of two 16-key chunks pack directly into the B-operand.
__global__ __launch_bounds__(256, 2) void k_flash(
    const unsigned short* __restrict__ qbuf, const unsigned short* __restrict__ kfull,
    const unsigned short* __restrict__ vfull, unsigned short* __restrict__ attnout)
{
  __shared__ char smem[65536];
  unsigned short* Kl = (unsigned short*)smem;            // [128 keys][128 hd], 16B-unit XOR swizzle
  unsigned short* Vt = (unsigned short*)(smem + 32768);  // [128 d][128 keys], permuted+swizzled
  const int tid = threadIdx.x;
  const int l = tid & 63, w = tid >> 6;
  const int l15 = l & 15, g = l >> 4, l7 = l & 7;
  const int qt = blockIdx.x, bh = blockIdx.y;
  const int b = bh >> 4, h = bh & 15;

  short8 qf[4];
  {
    const int qrow = qt * 64 + w * 16 + l15;
    const unsigned short* qp = qbuf + ((size_t)(b * 2048 + qrow)) * 2048 + h * 128 + g * 8;
    qf[0] = *(const short8*)(qp);
    qf[1] = *(const short8*)(qp + 32);
    qf[2] = *(const short8*)(qp + 64);
    qf[3] = *(const short8*)(qp + 96);
  }
  f32x4 o[8];
#pragma unroll
  for (int d = 0; d < 8; ++d)
#pragma unroll
    for (int e = 0; e < 4; ++e) o[d][e] = 0.f;
  float m = -3.0e38f, lsum = 0.f;

  const int srowK = l >> 4;   // row within 4-row staging chunk
  const int suK = l & 15;     // 16B unit

  for (int t = 0; t < 32; ++t) {
    const size_t kt0 = (size_t)t * 128;
    const unsigned short* kb = kfull + ((size_t)b * 4096 + kt0) * 2048 + h * 128;
    const unsigned short* vb = vfull + ((size_t)b * 4096 + kt0) * 2048 + h * 128;
    // --- stage K via global_load_lds, source pre-swizzled (rule #21) ---
#pragma unroll
    for (int ci = 0; ci < 8; ++ci) {
      const int c = w * 8 + ci;            // 1KB chunk = 4 rows
      const int row = c * 4 + srowK;
      const int ucol = (suK ^ (row & 7)) * 8;
      GLD16(kb + (size_t)row * 2048 + ucol, &Kl[c * 512]);
    }
    // --- stage V^T via register transpose, packed b64 writes ---
#pragma unroll
    for (int p = 0; p < 2; ++p) {
      const int task = tid + p * 256;
      const int g4 = task & 31;            // key group (4 keys)
      const int dc = task >> 5;            // d chunk (8 d)
      const unsigned short* vp = vb + (size_t)(g4 * 4) * 2048 + dc * 8;
      short8 r0 = *(const short8*)(vp);
      short8 r1 = *(const short8*)(vp + 2048);
      short8 r2 = *(const short8*)(vp + 4096);
      short8 r3 = *(const short8*)(vp + 6144);
      const int vcol4 = (g4 & ~7) | ((g4 & 3) << 1) | ((g4 >> 2) & 1);  // column permute
#pragma unroll
      for (int d = 0; d < 8; ++d) {
        const int row = dc * 8 + d;
        short4_ pk; pk[0] = r0[d]; pk[1] = r1[d]; pk[2] = r2[d]; pk[3] = r3[d];
        const int unit16 = (vcol4 >> 1) ^ (row & 7);
        *(short4_*)((char*)Vt + row * 256 + unit16 * 16 + (vcol4 & 1) * 8) = pk;
      }
    }
    __syncthreads();
    // --- QK^T (swapped): sc[kc] rows=keys, col=q ---
    f32x4 sc[8];
#pragma unroll
    for (int kc = 0; kc < 8; ++kc) {
      f32x4 a4;
#pragma unroll
      for (int e = 0; e < 4; ++e) a4[e] = 0.f;
      const int row = kc * 16 + l15;
#pragma unroll
      for (int kk = 0; kk < 4; ++kk) {
        const int unit = (kk * 4 + g) ^ (row & 7);
        short8 af = *(const short8*)((const char*)Kl + row * 256 + unit * 16);
        a4 = __builtin_amdgcn_mfma_f32_16x16x32_bf16(af, qf[kk], a4, 0, 0, 0);
      }
      sc[kc] = a4;
    }
    // --- online softmax (per-q stats lane-local after xor-16/32 reduce) ---
    float tm = -3.0e38f;
#pragma unroll
    for (int kc = 0; kc < 8; ++kc)
#pragma unroll
      for (int i = 0; i < 4; ++i) tm = fmaxf(tm, sc[kc][i]);
    tm = fmaxf(tm, __shfl_xor(tm, 16, 64));
    tm = fmaxf(tm, __shfl_xor(tm, 32, 64));
    const float mnew = fmaxf(m, tm);
    const float f = exp2f(C2 * (m - mnew));
    m = mnew;
    float psum = 0.f;
    short8 pf[4];
#pragma unroll
    for (int c = 0; c < 4; ++c) {
#pragma unroll
      for (int i = 0; i < 4; ++i) {
        const float p0 = exp2f(C2 * (sc[2 * c][i] - mnew));
        const float p1 = exp2f(C2 * (sc[2 * c + 1][i] - mnew));
        psum += p0 + p1;
        pf[c][i] = (short)f2bf(p0);
        pf[c][i + 4] = (short)f2bf(p1);
      }
    }
    psum += __shfl_xor(psum, 16, 64);
    psum += __shfl_xor(psum, 32, 64);
    lsum = lsum * f + psum;
#pragma unroll
    for (int d = 0; d < 8; ++d)
#pragma unroll
      for (int e = 0; e < 4; ++e) o[d][e] *= f;
    // --- PV: O^T += V^T * P^T (16x16x32, 4 super-chunks of 32 keys) ---
#pragma unroll
    for (int c = 0; c < 4; ++c) {
#pragma unroll
      for (int d = 0; d < 8; ++d) {
        const int row = d * 16 + l15;
        const int unit = (4 * c + g) ^ l7;
        short8 vf = *(const short8*)((const char*)Vt + row * 256 + unit * 16);
        o[d] = __builtin_amdgcn_mfma_f32_16x16x32_bf16(vf, pf[c], o[d], 0, 0, 0);
      }
    }
    __syncthreads();
  }
  // --- epilogue: normalize, transpose via LDS, coalesced bf16 store ---
  const float inv = 1.0f / lsum;
  float* ep = (float*)smem;                 // [64 q][132 f32]
#pragma unroll
  for (int d = 0; d < 8; ++d) {
    f32x4 tv;
#pragma unroll
    for (int e = 0; e < 4; ++e) tv[e] = o[d][e] * inv;
    *(f32x4*)(ep + (w * 16 + l15) * 132 + d * 16 + g * 4) = tv;
  }
  __syncthreads();
#pragma unroll
  for (int p = 0; p < 4; ++p) {
    const int task = tid + p * 256;
    const int row = task >> 4, ch = task & 15;
    const float* sp = ep + row * 132 + ch * 8;
    short8 ov;
#pragma unroll
    for (int j = 0; j < 8; ++j) ov[j] = (short)f2bf(sp[j]);
    const int qg = qt * 64 + row;
    *(short8*)(attnout + ((size_t)(b * 2048 + qg)) * 2048 + h * 128 + ch * 8) = ov;
  }
}

// ---------------- host launcher ----------------
extern "C" void kernel_launch(void* const* d_in, const int* in_sizes, int n_in,
                              void* d_out, int out_size, void* d_ws, size_t ws_size,
                              hipStream_t stream)
{
  const float* x  = (const float*)d_in[0];
  const float* ck = (const float*)d_in[1];
  const float* cv = (const float*)d_in[2];
  const float* wq = (const float*)d_in[3];
  const float* bq = (const float*)d_in[4];
  const float* wk = (const float*)d_in[5];
  const float* bk = (const float*)d_in[6];
  const float* wv = (const float*)d_in[7];
  const float* bv = (const float*)d_in[8];
  const float* wo = (const float*)d_in[9];
  const float* bo = (const float*)d_in[10];
  float* out = (float*)d_out;

  char* ws = (char*)d_ws;
  unsigned short* xbf   = (unsigned short*)(ws);                 // 16 MB  [4096][2048]
  unsigned short* wqkvT = (unsigned short*)(ws + 16777216ull);   // 24 MB  [6144][2048]
  unsigned short* woT   = (unsigned short*)(ws + 41943040ull);   // 8 MB   [2048][2048]
  unsigned short* qbuf  = (unsigned short*)(ws + 50331648ull);   // 16 MB  [4096][2048]
  unsigned short* kfull = (unsigned short*)(ws + 67108864ull);   // 32 MB  [2][4096][2048]
  unsigned short* vfull = (unsigned short*)(ws + 100663296ull);  // 32 MB
  unsigned short* aout  = (unsigned short*)(ws + 134217728ull);  // 16 MB  (end 151 MB)

  k_transpose_w<<<dim3(32, 32, 4), 256, 0, stream>>>(wq, wk, wv, wo, wqkvT, woT);
  k_convert<<<dim3(4096, 3), 256, 0, stream>>>(x, ck, cv, xbf, kfull, vfull);
  k_gemm<0><<<dim3(48, 32), 256, 0, stream>>>(xbf, wqkvT, qbuf, kfull, vfull, nullptr,
                                              bq, bk, bv, 2048);
  k_flash<<<dim3(32, 32), 256, 0, stream>>>(qbuf, kfull, vfull, aout);
  k_gemm<1><<<dim3(16, 32), 256, 0, stream>>>(aout, woT, nullptr, nullptr, nullptr, out,
                                              bo, nullptr, nullptr, 2048);
}

// Round 2
// 555.711 us; speedup vs baseline: 1.2288x; 1.2288x over previous
//
#include <hip/hip_runtime.h>

typedef __attribute__((ext_vector_type(8))) short short8;
typedef __attribute__((ext_vector_type(4))) short short4_;
typedef __attribute__((ext_vector_type(4))) float f32x4;

#define AS1 __attribute__((address_space(1)))
#define AS3 __attribute__((address_space(3)))
#define GLD16(g, l) __builtin_amdgcn_global_load_lds((const AS1 void*)(g), (AS3 void*)(l), 16, 0, 0)

#define C2 0.12751743f  /* log2(e)/sqrt(128) */

__device__ __forceinline__ unsigned short f2bf(float f) {
  unsigned int u = __float_as_uint(f);
  u += 0x7fffu + ((u >> 16) & 1u);   // RNE
  return (unsigned short)(u >> 16);
}

// ---------------- weight transpose: [K][N] f32 -> [N][K] bf16 ----------------
__global__ __launch_bounds__(256) void k_transpose_w(
    const float* __restrict__ wq, const float* __restrict__ wk,
    const float* __restrict__ wv, const float* __restrict__ wo,
    unsigned short* __restrict__ wqkvT, unsigned short* __restrict__ woT)
{
  __shared__ float tile[64][65];
  const int z = blockIdx.z;
  const float* src = (z == 0) ? wq : (z == 1) ? wk : (z == 2) ? wv : wo;
  unsigned short* dst = (z == 3) ? woT : (wqkvT + (size_t)z * 2048 * 2048);
  const int k0 = blockIdx.y * 64, n0 = blockIdx.x * 64;
  const int tid = threadIdx.x;
#pragma unroll
  for (int p = 0; p < 4; ++p) {
    const int r = p * 16 + (tid >> 4);
    const int c = (tid & 15) * 4;
    f32x4 v = *(const f32x4*)(src + (size_t)(k0 + r) * 2048 + n0 + c);
    tile[r][c + 0] = v[0]; tile[r][c + 1] = v[1];
    tile[r][c + 2] = v[2]; tile[r][c + 3] = v[3];
  }
  __syncthreads();
#pragma unroll
  for (int p = 0; p < 2; ++p) {
    const int task = tid + p * 256;
    const int n = task >> 3;
    const int kc = (task & 7) * 8;
    short8 ov;
#pragma unroll
    for (int j = 0; j < 8; ++j) ov[j] = (short)f2bf(tile[kc + j][n]);
    *(short8*)(dst + (size_t)(n0 + n) * 2048 + k0 + kc) = ov;
  }
}

// ------------- convert x / cache_k / cache_v f32 -> bf16 (cache into concat KV) -------------
__global__ __launch_bounds__(256) void k_convert(
    const float* __restrict__ x, const float* __restrict__ ck, const float* __restrict__ cv,
    unsigned short* __restrict__ xbf, unsigned short* __restrict__ kfull,
    unsigned short* __restrict__ vfull)
{
  const int z = blockIdx.y;
  const size_t idx = ((size_t)blockIdx.x * 256 + threadIdx.x) * 8;
  const float* src = (z == 0) ? x : (z == 1) ? ck : cv;
  f32x4 a = *(const f32x4*)(src + idx);
  f32x4 b = *(const f32x4*)(src + idx + 4);
  short8 ov;
#pragma unroll
  for (int j = 0; j < 4; ++j) { ov[j] = (short)f2bf(a[j]); ov[j + 4] = (short)f2bf(b[j]); }
  unsigned short* dp; size_t di;
  if (z == 0) { dp = xbf; di = idx; }
  else {
    const size_t r = idx >> 11, cl = idx & 2047;
    const size_t orow = r + (r & ~(size_t)2047);   // cache rows -> [b*4096 + p]
    di = orow * 2048 + cl;
    dp = (z == 1) ? kfull : vfull;
  }
  *(short8*)(dp + di) = ov;
}

// ---------------- GEMM: C[M,N] = A[M,K] * BT[N,K]^T + bias ----------------
template <int MODE>
__global__ __launch_bounds__(256, 2) void k_gemm(
    const unsigned short* __restrict__ A, const unsigned short* __restrict__ BT,
    unsigned short* __restrict__ Oq, unsigned short* __restrict__ Ok,
    unsigned short* __restrict__ Ov, float* __restrict__ Of,
    const float* __restrict__ b0, const float* __restrict__ b1,
    const float* __restrict__ b2, int K)
{
  __shared__ unsigned short Ah[128 * 32];
  __shared__ unsigned short Bh[128 * 32];
  const int tid = threadIdx.x;
  const int l = tid & 63, w = tid >> 6;
  const int l15 = l & 15, g = l >> 4;
  const int wr = (w >> 1) * 64, wc = (w & 1) * 64;
  const int bm = blockIdx.y, bn = blockIdx.x;
  const unsigned short* Ab = A + (size_t)bm * 128 * K;
  const unsigned short* Bb = BT + (size_t)bn * 128 * K;
  const int srow = l >> 2;
  const int scol = (l & 3) * 8;
  f32x4 acc[4][4];
#pragma unroll
  for (int i = 0; i < 4; ++i)
#pragma unroll
    for (int j = 0; j < 4; ++j)
#pragma unroll
      for (int e = 0; e < 4; ++e) acc[i][j][e] = 0.f;

  for (int kt = 0; kt < K; kt += 32) {
#pragma unroll
    for (int cc = 0; cc < 2; ++cc) {
      const int c = w + cc * 4;
      GLD16(Ab + (size_t)(c * 16 + srow) * K + kt + scol, &Ah[c * 512]);
      GLD16(Bb + (size_t)(c * 16 + srow) * K + kt + scol, &Bh[c * 512]);
    }
    __syncthreads();
    short8 af[4], bf[4];
#pragma unroll
    for (int i = 0; i < 4; ++i) {
      af[i] = *(const short8*)&Ah[(wr + i * 16 + l15) * 32 + g * 8];
      bf[i] = *(const short8*)&Bh[(wc + i * 16 + l15) * 32 + g * 8];
    }
#pragma unroll
    for (int i = 0; i < 4; ++i)
#pragma unroll
      for (int j = 0; j < 4; ++j)
        acc[i][j] = __builtin_amdgcn_mfma_f32_16x16x32_bf16(af[i], bf[j], acc[i][j], 0, 0, 0);
    __syncthreads();
  }

  const int rbase = bm * 128 + wr + g * 4;
  if (MODE == 0) {
    const int nglob = bn * 128;
    const int which = nglob >> 11;
    const int ncol0 = nglob & 2047;
    unsigned short* dst = (which == 0) ? Oq : (which == 1) ? Ok : Ov;
    const float* bias = (which == 0) ? b0 : (which == 1) ? b1 : b2;
#pragma unroll
    for (int j = 0; j < 4; ++j) {
      const int cc = ncol0 + wc + j * 16 + l15;
      const float bb = bias[cc];
#pragma unroll
      for (int i = 0; i < 4; ++i) {
#pragma unroll
        for (int ii = 0; ii < 4; ++ii) {
          const int rr = rbase + i * 16 + ii;
          const size_t orow = (which == 0) ? (size_t)rr
                                           : (size_t)(rr + (rr & ~2047) + 2048);
          dst[orow * 2048 + cc] = f2bf(acc[i][j][ii] + bb);
        }
      }
    }
  } else {
#pragma unroll
    for (int j = 0; j < 4; ++j) {
      const int cc = bn * 128 + wc + j * 16 + l15;
      const float bb = b0[cc];
#pragma unroll
      for (int i = 0; i < 4; ++i) {
#pragma unroll
        for (int ii = 0; ii < 4; ++ii) {
          const int rr = rbase + i * 16 + ii;
          Of[(size_t)rr * 2048 + cc] = acc[i][j][ii] + bb;
        }
      }
    }
  }
}

// ---------------- flash attention (v2) ----------------
// QBLK=128 (4 waves x 32 q-rows: 2 groups of 16 -> every K/V LDS read feeds 2 MFMAs).
// KBLK=64, double-buffered LDS (2 x 32KB). One barrier per tile.
// Swapped QK^T (S^T = K x Q^T) keeps softmax stats lane-local; V^T staged with
// column permutation so P D-regs feed PV's B-operand directly.
__global__ __launch_bounds__(256, 2) void k_flash(
    const unsigned short* __restrict__ qbuf, const unsigned short* __restrict__ kfull,
    const unsigned short* __restrict__ vfull, unsigned short* __restrict__ attnout)
{
  __shared__ char smem[65536];
  const int tid = threadIdx.x;
  const int l = tid & 63, w = tid >> 6;
  const int l15 = l & 15, g = l >> 4;
  const int qt = blockIdx.x, bh = blockIdx.y;
  const int b = bh >> 4, h = bh & 15;

  // Q fragments for 2 groups of 16 rows
  short8 qfA[4], qfB[4];
  {
    const int qrowA = qt * 128 + w * 32 + l15;
    const unsigned short* qpA = qbuf + ((size_t)(b * 2048 + qrowA)) * 2048 + h * 128 + g * 8;
    const unsigned short* qpB = qpA + 16 * 2048;
#pragma unroll
    for (int kk = 0; kk < 4; ++kk) {
      qfA[kk] = *(const short8*)(qpA + kk * 32);
      qfB[kk] = *(const short8*)(qpB + kk * 32);
    }
  }
  f32x4 oA[8], oB[8];
#pragma unroll
  for (int d = 0; d < 8; ++d)
#pragma unroll
    for (int e = 0; e < 4; ++e) { oA[d][e] = 0.f; oB[d][e] = 0.f; }
  float mA = -1e30f, mB = -1e30f, lsA = 0.f, lsB = 0.f;

  const unsigned short* kbase = kfull + ((size_t)b * 4096) * 2048 + h * 128;
  const unsigned short* vbase = vfull + ((size_t)b * 4096) * 2048 + h * 128;

  // V staging mapping: key-group of 4 varies fastest (even bank spread on writes)
  const int vg4 = tid & 15;
  const int vdc = tid >> 4;
  const int vcol4 = (vg4 & 8) | ((vg4 & 3) << 1) | ((vg4 >> 2) & 1);  // column permute
  const int vu = vcol4 >> 1;
  const int vhalf = (vcol4 & 1) * 8;
  // K staging: wave w stages chunks w*4..w*4+3 (1KB = 4 rows each)
  const int ksrow = l >> 4, ksu = l & 15;

  auto STAGEK = [&](int t, char* Kn) {
    const unsigned short* kb = kbase + (size_t)t * 64 * 2048;
#pragma unroll
    for (int ci = 0; ci < 4; ++ci) {
      const int c = w * 4 + ci;
      const int row = c * 4 + ksrow;
      GLD16(kb + (size_t)row * 2048 + ((ksu ^ (row & 7)) * 8), Kn + c * 1024);
    }
  };
  auto VLOAD = [&](int t, short8* r) {
    const unsigned short* vp = vbase + ((size_t)t * 64 + vg4 * 4) * 2048 + vdc * 8;
    r[0] = *(const short8*)(vp);
    r[1] = *(const short8*)(vp + 2048);
    r[2] = *(const short8*)(vp + 4096);
    r[3] = *(const short8*)(vp + 6144);
  };
  auto VWRITE = [&](char* Vn, short8* r) {
#pragma unroll
    for (int d = 0; d < 8; ++d) {
      const int row = vdc * 8 + d;
      const int mm = (d ^ vdc) & 7;               // (row ^ row>>3) & 7
      short4_ pk; pk[0] = r[0][d]; pk[1] = r[1][d]; pk[2] = r[2][d]; pk[3] = r[3][d];
      *(short4_*)(Vn + row * 128 + ((vu ^ mm) * 16) + vhalf) = pk;
    }
  };

  // prologue: stage tile 0 into buffer 0
  {
    short8 vr[4];
    STAGEK(0, smem);
    VLOAD(0, vr);
    VWRITE(smem + 16384, vr);
    __syncthreads();
  }

  for (int t = 0; t < 64; ++t) {
    char* Kc = smem + (t & 1) * 32768;
    char* Vc = Kc + 16384;
    char* Kn = smem + ((t + 1) & 1) * 32768;
    char* Vn = Kn + 16384;
    const bool pre = (t + 1) < 64;
    short8 vr[4];
    if (pre) {
      STAGEK(t + 1, Kn);   // async DMA into other buffer
      VLOAD(t + 1, vr);    // reg-staged; latency hidden under QK^T
    }
    // --- QK^T (swapped): scX[kc] rows=keys, col=q ---
    f32x4 scA[4], scB[4];
    __builtin_amdgcn_s_setprio(1);
#pragma unroll
    for (int kc = 0; kc < 4; ++kc) {
      f32x4 a0, a1;
#pragma unroll
      for (int e = 0; e < 4; ++e) { a0[e] = 0.f; a1[e] = 0.f; }
      const int rowk = kc * 16 + l15;
      const int mk = rowk & 7;
#pragma unroll
      for (int kk = 0; kk < 4; ++kk) {
        short8 kf = *(const short8*)(Kc + rowk * 256 + (((kk * 4 + g) ^ mk) * 16));
        a0 = __builtin_amdgcn_mfma_f32_16x16x32_bf16(kf, qfA[kk], a0, 0, 0, 0);
        a1 = __builtin_amdgcn_mfma_f32_16x16x32_bf16(kf, qfB[kk], a1, 0, 0, 0);
      }
      scA[kc] = a0; scB[kc] = a1;
    }
    __builtin_amdgcn_s_setprio(0);
    if (pre) VWRITE(Vn, vr);   // write-late into other buffer

    // --- online softmax, group A then B (T13 defer-max, THR=16) ---
    short8 pfA[2], pfB[2];
    {
      float tm = fmaxf(fmaxf(scA[0][0], scA[0][1]), fmaxf(scA[0][2], scA[0][3]));
#pragma unroll
      for (int kc = 1; kc < 4; ++kc)
        tm = fmaxf(tm, fmaxf(fmaxf(scA[kc][0], scA[kc][1]), fmaxf(scA[kc][2], scA[kc][3])));
      tm = fmaxf(tm, __shfl_xor(tm, 16, 64));
      tm = fmaxf(tm, __shfl_xor(tm, 32, 64));
      if (!__all(tm <= mA + 16.f)) {
        const float mn = fmaxf(mA, tm);
        const float f = exp2f(C2 * (mA - mn));
        mA = mn; lsA *= f;
#pragma unroll
        for (int d = 0; d < 8; ++d)
#pragma unroll
          for (int e = 0; e < 4; ++e) oA[d][e] *= f;
      }
      const float mc = C2 * mA;
      float ps = 0.f;
#pragma unroll
      for (int c = 0; c < 2; ++c) {
#pragma unroll
        for (int i = 0; i < 4; ++i) {
          const float p0 = exp2f(fmaf(C2, scA[2 * c][i], -mc));
          const float p1 = exp2f(fmaf(C2, scA[2 * c + 1][i], -mc));
          ps += p0 + p1;
          pfA[c][i] = (short)f2bf(p0);
          pfA[c][i + 4] = (short)f2bf(p1);
        }
      }
      ps += __shfl_xor(ps, 16, 64);
      ps += __shfl_xor(ps, 32, 64);
      lsA += ps;
    }
    {
      float tm = fmaxf(fmaxf(scB[0][0], scB[0][1]), fmaxf(scB[0][2], scB[0][3]));
#pragma unroll
      for (int kc = 1; kc < 4; ++kc)
        tm = fmaxf(tm, fmaxf(fmaxf(scB[kc][0], scB[kc][1]), fmaxf(scB[kc][2], scB[kc][3])));
      tm = fmaxf(tm, __shfl_xor(tm, 16, 64));
      tm = fmaxf(tm, __shfl_xor(tm, 32, 64));
      if (!__all(tm <= mB + 16.f)) {
        const float mn = fmaxf(mB, tm);
        const float f = exp2f(C2 * (mB - mn));
        mB = mn; lsB *= f;
#pragma unroll
        for (int d = 0; d < 8; ++d)
#pragma unroll
          for (int e = 0; e < 4; ++e) oB[d][e] *= f;
      }
      const float mc = C2 * mB;
      float ps = 0.f;
#pragma unroll
      for (int c = 0; c < 2; ++c) {
#pragma unroll
        for (int i = 0; i < 4; ++i) {
          const float p0 = exp2f(fmaf(C2, scB[2 * c][i], -mc));
          const float p1 = exp2f(fmaf(C2, scB[2 * c + 1][i], -mc));
          ps += p0 + p1;
          pfB[c][i] = (short)f2bf(p0);
          pfB[c][i + 4] = (short)f2bf(p1);
        }
      }
      ps += __shfl_xor(ps, 16, 64);
      ps += __shfl_xor(ps, 32, 64);
      lsB += ps;
    }

    // --- PV: O^T += V^T * P^T ---
    __builtin_amdgcn_s_setprio(1);
#pragma unroll
    for (int c = 0; c < 2; ++c) {
#pragma unroll
      for (int d = 0; d < 8; ++d) {
        const int rowv = d * 16 + l15;
        const int mv = (rowv ^ (rowv >> 3)) & 7;
        short8 vf = *(const short8*)(Vc + rowv * 128 + ((((c * 4 + g) ^ mv)) * 16));
        oA[d] = __builtin_amdgcn_mfma_f32_16x16x32_bf16(vf, pfA[c], oA[d], 0, 0, 0);
        oB[d] = __builtin_amdgcn_mfma_f32_16x16x32_bf16(vf, pfB[c], oB[d], 0, 0, 0);
      }
    }
    __builtin_amdgcn_s_setprio(0);
    __syncthreads();
  }

  // --- epilogue: normalize, bf16 transpose via LDS, coalesced store ---
  __syncthreads();
  const float invA = 1.0f / lsA, invB = 1.0f / lsB;
  char* ep = smem;   // [128 q][136 bf16] = 34816 B
#pragma unroll
  for (int d = 0; d < 8; ++d) {
    short4_ pa, pb;
#pragma unroll
    for (int e = 0; e < 4; ++e) {
      pa[e] = (short)f2bf(oA[d][e] * invA);
      pb[e] = (short)f2bf(oB[d][e] * invB);
    }
    const int colb = (d * 16 + g * 4) * 2;
    *(short4_*)(ep + (w * 32 + l15) * 272 + colb) = pa;
    *(short4_*)(ep + (w * 32 + 16 + l15) * 272 + colb) = pb;
  }
  __syncthreads();
#pragma unroll
  for (int i = 0; i < 8; ++i) {
    const int task = tid + i * 256;
    const int row = task >> 4, un = task & 15;
    short8 ov = *(const short8*)(ep + row * 272 + un * 16);
    const int qg = qt * 128 + row;
    *(short8*)(attnout + ((size_t)(b * 2048 + qg)) * 2048 + h * 128 + un * 8) = ov;
  }
}

// ---------------- host launcher ----------------
extern "C" void kernel_launch(void* const* d_in, const int* in_sizes, int n_in,
                              void* d_out, int out_size, void* d_ws, size_t ws_size,
                              hipStream_t stream)
{
  const float* x  = (const float*)d_in[0];
  const float* ck = (const float*)d_in[1];
  const float* cv = (const float*)d_in[2];
  const float* wq = (const float*)d_in[3];
  const float* bq = (const float*)d_in[4];
  const float* wk = (const float*)d_in[5];
  const float* bk = (const float*)d_in[6];
  const float* wv = (const float*)d_in[7];
  const float* bv = (const float*)d_in[8];
  const float* wo = (const float*)d_in[9];
  const float* bo = (const float*)d_in[10];
  float* out = (float*)d_out;

  char* ws = (char*)d_ws;
  unsigned short* xbf   = (unsigned short*)(ws);                 // 16 MB
  unsigned short* wqkvT = (unsigned short*)(ws + 16777216ull);   // 24 MB
  unsigned short* woT   = (unsigned short*)(ws + 41943040ull);   // 8 MB
  unsigned short* qbuf  = (unsigned short*)(ws + 50331648ull);   // 16 MB
  unsigned short* kfull = (unsigned short*)(ws + 67108864ull);   // 32 MB
  unsigned short* vfull = (unsigned short*)(ws + 100663296ull);  // 32 MB
  unsigned short* aout  = (unsigned short*)(ws + 134217728ull);  // 16 MB

  k_transpose_w<<<dim3(32, 32, 4), 256, 0, stream>>>(wq, wk, wv, wo, wqkvT, woT);
  k_convert<<<dim3(4096, 3), 256, 0, stream>>>(x, ck, cv, xbf, kfull, vfull);
  k_gemm<0><<<dim3(48, 32), 256, 0, stream>>>(xbf, wqkvT, qbuf, kfull, vfull, nullptr,
                                              bq, bk, bv, 2048);
  k_flash<<<dim3(16, 32), 256, 0, stream>>>(qbuf, kfull, vfull, aout);
  k_gemm<1><<<dim3(16, 32), 256, 0, stream>>>(aout, woT, nullptr, nullptr, nullptr, out,
                                              bo, nullptr, nullptr, 2048);
}